// Round 2
// baseline (88.894 us; speedup 1.0000x reference)
//
#include <hip/hip_runtime.h>
#include <hip/hip_bf16.h>

// MaxPoolingMatching: out[b,l,p] = max_m cos( s1[b,l,:]∘k[p,:], s2[b,m,:]∘k[p,:] )
// B=16, L=256, D=256, P=20.
//
// v6: measured reality from rounds 0/1: the timed region = [268MB workspace
// poison-fill ≈42µs, harness-fixed, paid even with zero ws use] + [kernels
// ≈41µs]. So ws is free again -> prep2 restored (verbatim, round-0-verified).
// Main restructured for occupancy: the A-operand bf16(s2) lives in REGISTERS
// (af[2][8] = 64 VGPR/thread, loaded straight from s2bf; L2-resident via
// XCD-grouped block swizzle) -> X2's 128KB LDS deleted, LDS = 17KB, grid 512
// (b16 x lt8 x pgi4, l-tile 32), __launch_bounds__(512,4) -> 2 blocks/CU,
// 4 waves/SIMD (was 1 block, 2 waves/SIMD with 28 barriers). 2 barriers/p.
// K-loop LDS traffic/CU: 1.92MB -> 1.28MB (B-reads only).

#define B_DIM 16
#define L_DIM 256
#define D_DIM 256
#define P_DIM 20
#define EPS 1e-12f
#define LDP 264   // prep2 padded stride: 2-way bank aliasing only (free)

typedef __attribute__((ext_vector_type(8))) __bf16 bf16x8;
typedef __attribute__((ext_vector_type(4))) float f32x4;

__device__ __forceinline__ unsigned short f2bf(float x) {
  unsigned int u = __float_as_uint(x);
  u += 0x7fffu + ((u >> 16) & 1u);   // RNE
  return (unsigned short)(u >> 16);
}

// ---------------- prep2: MFMA norms + bf16 casts (round-0-verified) ----------------
// 256 blocks x 256 threads; block = (sentence = bid&1, 32-row tile = bid>>1)
__global__ __launch_bounds__(256)
void prep2(const float* __restrict__ s1, const float* __restrict__ s2,
           const float* __restrict__ kg,
           float* __restrict__ rn1, float* __restrict__ rn2,
           unsigned short* __restrict__ s1bf, unsigned short* __restrict__ s2bf) {
  __shared__ __align__(16) unsigned short QA[32 * LDP];  // bf16(s²) rows
  __shared__ __align__(16) unsigned short QB[32 * LDP];  // bf16(k²) rows (20 valid)
  const int tid = threadIdx.x, lane = tid & 63, wave = tid >> 6;
  const int lr = lane & 15, q = lane >> 4;
  const int sent = blockIdx.x & 1, t = blockIdx.x >> 1;   // t: 0..127
  const int r0 = t * 32, b = r0 >> 8;                     // 32 | 256 -> single b
  const float* src = sent ? s2 : s1;
  unsigned short* sbf = sent ? s2bf : s1bf;
  float* rn = sent ? rn2 : rn1;

  #pragma unroll
  for (int i = 0; i < 8; ++i) {
    const int row = i * 4 + wave;
    float4 sv = *(const float4*)(src + (size_t)(r0 + row) * D_DIM + lane * 4);
    unsigned int c0 = ((unsigned int)f2bf(sv.y) << 16) | f2bf(sv.x);
    unsigned int c1 = ((unsigned int)f2bf(sv.w) << 16) | f2bf(sv.z);
    *(uint2*)&sbf[(size_t)(r0 + row) * D_DIM + lane * 4] = make_uint2(c0, c1);
    unsigned int q0 = ((unsigned int)f2bf(sv.y * sv.y) << 16) | f2bf(sv.x * sv.x);
    unsigned int q1 = ((unsigned int)f2bf(sv.w * sv.w) << 16) | f2bf(sv.z * sv.z);
    *(uint2*)&QA[row * LDP + lane * 4] = make_uint2(q0, q1);
  }
  #pragma unroll
  for (int j = 0; j < 5; ++j) {
    const int row = wave * 5 + j;   // 0..19; rows 20..31 of QB stay garbage (masked)
    float4 kv = *(const float4*)(kg + row * D_DIM + lane * 4);
    unsigned int c0 = ((unsigned int)f2bf(kv.y * kv.y) << 16) | f2bf(kv.x * kv.x);
    unsigned int c1 = ((unsigned int)f2bf(kv.w * kv.w) << 16) | f2bf(kv.z * kv.z);
    *(uint2*)&QB[row * LDP + lane * 4] = make_uint2(c0, c1);
  }
  __syncthreads();

  // wave w: m-tile (w&1) of the 32 rows, n-tile (w>>1) of p∈[0,32)
  const int mt = wave & 1, nt = wave >> 1;
  f32x4 acc = {0.f, 0.f, 0.f, 0.f};
  #pragma unroll
  for (int ks = 0; ks < 8; ++ks) {
    const int cc = ks * 4 + q;
    bf16x8 a  = *(const bf16x8*)&QA[(mt * 16 + lr) * LDP + cc * 8];
    bf16x8 bb = *(const bf16x8*)&QB[(nt * 16 + lr) * LDP + cc * 8];
    acc = __builtin_amdgcn_mfma_f32_16x16x32_bf16(a, bb, acc, 0, 0, 0);
  }
  // C: row(reg) = sentence-row, col(lane) = p
  const int p = nt * 16 + lr;
  if (p < P_DIM) {
    #pragma unroll
    for (int r = 0; r < 4; ++r) {
      const int l = (r0 & 255) + mt * 16 + q * 4 + r;
      rn[((size_t)b * P_DIM + p) * L_DIM + l] = rsqrtf(fmaxf(acc[r], EPS));
    }
  }
}

// ---------------- main v6: A-in-registers, 17KB LDS, 2 blocks/CU ----------------
__global__ __launch_bounds__(512, 4)
void mpm_main(const unsigned short* __restrict__ s1bf,
              const unsigned short* __restrict__ s2bf,
              const float* __restrict__ kg, const float* __restrict__ rn1,
              const float* __restrict__ rn2, float* __restrict__ outg) {
  __shared__ __align__(16) unsigned short X1[32 * 256];  // 16KB bf16(s1*k^2), swizzled
  __shared__ float Wout[8 * 32];                          // 1KB per-wave maxes

  const int tid = threadIdx.x, lane = tid & 63, wave = tid >> 6;  // 8 waves
  const int lr = lane & 15, q = lane >> 4;

  // XCD-grouping swizzle (512 blocks, 8 XCDs): XCD x gets logical [64x,64x+64)
  // = 2 full b's -> s2bf[b] (128KB bf16) stays in that XCD's L2.
  const int bid = (int)((blockIdx.x >> 3) + (blockIdx.x & 7) * 64);
  const int pgi = bid & 3, lt = (bid >> 2) & 7, b = bid >> 5;
  const int l0 = lt * 32;

  // A-fragments in registers: af[mi][ks] = bf16(s2)[wave*32+mi*16+lr, ks*32+q*8 ..+8]
  bf16x8 af[2][8];
  {
    const unsigned short* s2b2 = s2bf + (size_t)b * (L_DIM * D_DIM);
    #pragma unroll
    for (int mi = 0; mi < 2; ++mi) {
      const unsigned short* rp = s2b2 + (size_t)(wave * 32 + mi * 16 + lr) * D_DIM + q * 8;
      #pragma unroll
      for (int ks = 0; ks < 8; ++ks)
        af[mi][ks] = *(const bf16x8*)(rp + ks * 32);
    }
  }

  // register-cache bf16(s1) tile: 4 rows per wave, 8B/lane
  uint2 s1r[4];
  {
    const unsigned short* s1b2 = s1bf + ((size_t)b * L_DIM + l0) * D_DIM;
    #pragma unroll
    for (int i = 0; i < 4; ++i)
      s1r[i] = *(const uint2*)(s1b2 + (size_t)(i * 8 + wave) * D_DIM + lane * 4);
  }

  #pragma unroll 1
  for (int pp = 0; pp < 5; ++pp) {
    const int p = pgi * 5 + pp;

    // build X1 = bf16( s1 * k^2 ), swizzled 8B stores (rn1 applied at output)
    {
      float4 kv = *(const float4*)(kg + (size_t)p * D_DIM + lane * 4);
      const float k0 = kv.x * kv.x, k1 = kv.y * kv.y, k2 = kv.z * kv.z, k3 = kv.w * kv.w;
      #pragma unroll
      for (int i = 0; i < 4; ++i) {
        const int row = i * 8 + wave;
        float x0 = __uint_as_float(s1r[i].x << 16)         * k0;
        float x1 = __uint_as_float(s1r[i].x & 0xffff0000u) * k1;
        float x2 = __uint_as_float(s1r[i].y << 16)         * k2;
        float x3 = __uint_as_float(s1r[i].y & 0xffff0000u) * k3;
        unsigned int c0 = ((unsigned int)f2bf(x1) << 16) | f2bf(x0);
        unsigned int c1 = ((unsigned int)f2bf(x3) << 16) | f2bf(x2);
        *(uint2*)&X1[row * 256 + (((lane >> 1) ^ row) << 3) + ((lane & 1) << 2)] =
            make_uint2(c0, c1);
      }
    }
    __syncthreads();   // X1 visible (prev p: all X1/Wout reads were done pre-barrier)

    // K-loop: wave computes C[32m x 32l], A from registers, B from LDS
    f32x4 acc[2][2];
    #pragma unroll
    for (int mi = 0; mi < 2; ++mi)
      #pragma unroll
      for (int li = 0; li < 2; ++li) acc[mi][li] = (f32x4){0.f, 0.f, 0.f, 0.f};

    #pragma unroll
    for (int ks = 0; ks < 8; ++ks) {
      const int cc = ks * 4 + q;
      bf16x8 bb[2];
      #pragma unroll
      for (int li = 0; li < 2; ++li) {
        const int l = li * 16 + lr;
        bb[li] = *(const bf16x8*)&X1[l * 256 + ((cc ^ l) << 3)];
      }
      #pragma unroll
      for (int li = 0; li < 2; ++li) {
        acc[0][li] = __builtin_amdgcn_mfma_f32_16x16x32_bf16(af[0][ks], bb[li], acc[0][li], 0, 0, 0);
        acc[1][li] = __builtin_amdgcn_mfma_f32_16x16x32_bf16(af[1][ks], bb[li], acc[1][li], 0, 0, 0);
      }
    }

    // epilogue: C row(reg) = m = wave*32 + mi*16 + q*4 + r ; col(lane) = l = li*16+lr
    float4 r20, r21;
    {
      const float* rn2b = rn2 + ((size_t)b * P_DIM + p) * L_DIM + wave * 32;
      r20 = *(const float4*)(rn2b + q * 4);
      r21 = *(const float4*)(rn2b + 16 + q * 4);
    }
    float v[2];
    #pragma unroll
    for (int li = 0; li < 2; ++li) {
      float t = -3.4e38f;
      t = fmaxf(t, fmaxf(acc[0][li][0] * r20.x, acc[1][li][0] * r21.x));
      t = fmaxf(t, fmaxf(acc[0][li][1] * r20.y, acc[1][li][1] * r21.y));
      t = fmaxf(t, fmaxf(acc[0][li][2] * r20.z, acc[1][li][2] * r21.z));
      t = fmaxf(t, fmaxf(acc[0][li][3] * r20.w, acc[1][li][3] * r21.w));
      t = fmaxf(t, __shfl_xor(t, 16));
      t = fmaxf(t, __shfl_xor(t, 32));
      v[li] = t;
    }
    if (q == 0) {
      #pragma unroll
      for (int li = 0; li < 2; ++li) Wout[wave * 32 + li * 16 + lr] = v[li];
    }
    __syncthreads();   // Wout visible; all X1 reads of this p done
    if (tid < 32) {
      float o = Wout[tid];
      #pragma unroll
      for (int w = 1; w < 8; ++w) o = fmaxf(o, Wout[w * 32 + tid]);
      const float r1 = rn1[((size_t)b * P_DIM + p) * L_DIM + l0 + tid];
      outg[((size_t)b * L_DIM + (l0 + tid)) * P_DIM + p] = o * r1;
    }
  }
}

extern "C" void kernel_launch(void* const* d_in, const int* in_sizes, int n_in,
                              void* d_out, int out_size, void* d_ws, size_t ws_size,
                              hipStream_t stream) {
  (void)in_sizes; (void)n_in; (void)out_size; (void)ws_size;
  const float* s1 = (const float*)d_in[0];
  const float* s2 = (const float*)d_in[1];
  const float* kg = (const float*)d_in[2];
  float* out = (float*)d_out;

  // ws: rn1 | rn2 (B*P*L f32 each) | s2bf | s1bf (B*L*D bf16 each)  ≈ 4.9 MB
  float* rn1 = (float*)d_ws;
  float* rn2 = rn1 + (size_t)B_DIM * P_DIM * L_DIM;
  unsigned short* s2bf = (unsigned short*)(rn2 + (size_t)B_DIM * P_DIM * L_DIM);
  unsigned short* s1bf = s2bf + (size_t)B_DIM * L_DIM * D_DIM;

  prep2<<<dim3(256), dim3(256), 0, stream>>>(s1, s2, kg, rn1, rn2, s1bf, s2bf);
  mpm_main<<<dim3(512), dim3(512), 0, stream>>>(s1bf, s2bf, kg, rn1, rn2, out);
}

// Round 3
// 82.297 us; speedup vs baseline: 1.0802x; 1.0802x over previous
//
#include <hip/hip_runtime.h>
#include <hip/hip_bf16.h>

// MaxPoolingMatching: out[b,l,p] = max_m cos( s1[b,l,:]∘k[p,:], s2[b,m,:]∘k[p,:] )
// B=16, L=256, D=256, P=20.
//
// v7: main is serialization-bound (floor ~8-10µs vs measured 33-42µs), so this
// round attacks the serial chain, not throughput:
//  - keep v6's A-in-registers (af[2][8]=64 VGPR; waves only ever read their own
//    32 m-rows, so X2-in-LDS was waste; K-loop LDS reads 48->32 per wave per p),
//  - revert to 64-l tiles / 256 blocks / 512 thr (v6's 512 blocks at 1 blk/CU
//    ran as 2 sequential rounds, doubling the latency-bound per-p chains),
//  - NEW: double-buffered X1 (2x32KB) -> ONE barrier per p (6 total, was ~21);
//    build(p+1) overlaps K-loop(p) in each wave's stream,
//  - NEW: all per-p global latencies hoisted: k^2 slices for all 5 p in regs
//    (20 VGPR), rn1 column preloaded in wave 0, rn2 issued at iteration top
//    (~2500cy before its epilogue use),
//  - __launch_bounds__(512,2): VGPR cap 256 (est ~180, no spill; v6's (512,4)
//    cap-128 was the likely spill/occupancy trap).
// LDS = 64KB X1 + 4KB Wout. prep2 unchanged (round-0-verified).

#define B_DIM 16
#define L_DIM 256
#define D_DIM 256
#define P_DIM 20
#define EPS 1e-12f
#define LDP 264   // prep2 padded stride: 2-way bank aliasing only (free)

typedef __attribute__((ext_vector_type(8))) __bf16 bf16x8;
typedef __attribute__((ext_vector_type(4))) float f32x4;

__device__ __forceinline__ unsigned short f2bf(float x) {
  unsigned int u = __float_as_uint(x);
  u += 0x7fffu + ((u >> 16) & 1u);   // RNE
  return (unsigned short)(u >> 16);
}

// ---------------- prep2: MFMA norms + bf16 casts (round-0-verified) ----------------
// 256 blocks x 256 threads; block = (sentence = bid&1, 32-row tile = bid>>1)
__global__ __launch_bounds__(256)
void prep2(const float* __restrict__ s1, const float* __restrict__ s2,
           const float* __restrict__ kg,
           float* __restrict__ rn1, float* __restrict__ rn2,
           unsigned short* __restrict__ s1bf, unsigned short* __restrict__ s2bf) {
  __shared__ __align__(16) unsigned short QA[32 * LDP];  // bf16(s²) rows
  __shared__ __align__(16) unsigned short QB[32 * LDP];  // bf16(k²) rows (20 valid)
  const int tid = threadIdx.x, lane = tid & 63, wave = tid >> 6;
  const int lr = lane & 15, q = lane >> 4;
  const int sent = blockIdx.x & 1, t = blockIdx.x >> 1;   // t: 0..127
  const int r0 = t * 32, b = r0 >> 8;                     // 32 | 256 -> single b
  const float* src = sent ? s2 : s1;
  unsigned short* sbf = sent ? s2bf : s1bf;
  float* rn = sent ? rn2 : rn1;

  #pragma unroll
  for (int i = 0; i < 8; ++i) {
    const int row = i * 4 + wave;
    float4 sv = *(const float4*)(src + (size_t)(r0 + row) * D_DIM + lane * 4);
    unsigned int c0 = ((unsigned int)f2bf(sv.y) << 16) | f2bf(sv.x);
    unsigned int c1 = ((unsigned int)f2bf(sv.w) << 16) | f2bf(sv.z);
    *(uint2*)&sbf[(size_t)(r0 + row) * D_DIM + lane * 4] = make_uint2(c0, c1);
    unsigned int q0 = ((unsigned int)f2bf(sv.y * sv.y) << 16) | f2bf(sv.x * sv.x);
    unsigned int q1 = ((unsigned int)f2bf(sv.w * sv.w) << 16) | f2bf(sv.z * sv.z);
    *(uint2*)&QA[row * LDP + lane * 4] = make_uint2(q0, q1);
  }
  #pragma unroll
  for (int j = 0; j < 5; ++j) {
    const int row = wave * 5 + j;   // 0..19; rows 20..31 of QB stay garbage (masked)
    float4 kv = *(const float4*)(kg + row * D_DIM + lane * 4);
    unsigned int c0 = ((unsigned int)f2bf(kv.y * kv.y) << 16) | f2bf(kv.x * kv.x);
    unsigned int c1 = ((unsigned int)f2bf(kv.w * kv.w) << 16) | f2bf(kv.z * kv.z);
    *(uint2*)&QB[row * LDP + lane * 4] = make_uint2(c0, c1);
  }
  __syncthreads();

  // wave w: m-tile (w&1) of the 32 rows, n-tile (w>>1) of p∈[0,32)
  const int mt = wave & 1, nt = wave >> 1;
  f32x4 acc = {0.f, 0.f, 0.f, 0.f};
  #pragma unroll
  for (int ks = 0; ks < 8; ++ks) {
    const int cc = ks * 4 + q;
    bf16x8 a  = *(const bf16x8*)&QA[(mt * 16 + lr) * LDP + cc * 8];
    bf16x8 bb = *(const bf16x8*)&QB[(nt * 16 + lr) * LDP + cc * 8];
    acc = __builtin_amdgcn_mfma_f32_16x16x32_bf16(a, bb, acc, 0, 0, 0);
  }
  // C: row(reg) = sentence-row, col(lane) = p
  const int p = nt * 16 + lr;
  if (p < P_DIM) {
    #pragma unroll
    for (int r = 0; r < 4; ++r) {
      const int l = (r0 & 255) + mt * 16 + q * 4 + r;
      rn[((size_t)b * P_DIM + p) * L_DIM + l] = rsqrtf(fmaxf(acc[r], EPS));
    }
  }
}

// ---------------- main v7: A-regs + X1 double-buffer, 1 barrier/p ----------------
__global__ __launch_bounds__(512, 2)
void mpm_main(const unsigned short* __restrict__ s1bf,
              const unsigned short* __restrict__ s2bf,
              const float* __restrict__ kg, const float* __restrict__ rn1,
              const float* __restrict__ rn2, float* __restrict__ outg) {
  __shared__ __align__(16) unsigned short X1[2][64 * 256];  // 2 x 32KB, swizzled
  __shared__ float Wout[2][8 * 64];                         // 2 x 2KB per-wave maxes

  const int tid = threadIdx.x, lane = tid & 63, wave = tid >> 6;  // 8 waves
  const int lr = lane & 15, q = lane >> 4;

  // XCD-grouping swizzle (256 blocks, 8 XCDs): XCD x gets logical [32x,32x+32)
  // = 2 full b's -> s2bf[b] reads stay in that XCD's L2.
  const int bid = (int)((blockIdx.x >> 3) + (blockIdx.x & 7) * 32);
  const int pgi = bid & 3, lt = (bid >> 2) & 3, b = bid >> 4;
  const int l0 = lt * 64;

  // A-fragments in registers: af[mi][ks] = bf16(s2)[wave*32+mi*16+lr, ks*32+q*8 ..+8]
  bf16x8 af[2][8];
  {
    const unsigned short* s2b2 = s2bf + (size_t)b * (L_DIM * D_DIM);
    #pragma unroll
    for (int mi = 0; mi < 2; ++mi) {
      const unsigned short* rp = s2b2 + (size_t)(wave * 32 + mi * 16 + lr) * D_DIM + q * 8;
      #pragma unroll
      for (int ks = 0; ks < 8; ++ks)
        af[mi][ks] = *(const bf16x8*)(rp + ks * 32);
    }
  }

  // register-cache bf16(s1): 8 rows per wave (l0 .. l0+63), 8B/lane
  uint2 s1r[8];
  {
    const unsigned short* s1b2 = s1bf + ((size_t)b * L_DIM + l0) * D_DIM;
    #pragma unroll
    for (int i = 0; i < 8; ++i)
      s1r[i] = *(const uint2*)(s1b2 + (size_t)(i * 8 + wave) * D_DIM + lane * 4);
  }

  // k^2 per-lane slices for this block's 5 p (hoisted off the per-p path)
  float4 kv2[5];
  #pragma unroll
  for (int j = 0; j < 5; ++j) {
    float4 t = *(const float4*)(kg + (size_t)(pgi * 5 + j) * D_DIM + lane * 4);
    kv2[j] = make_float4(t.x * t.x, t.y * t.y, t.z * t.z, t.w * t.w);
  }

  // rn1 column for the output threads (wave 0 == tid<64), hoisted
  float rn1v[5];
  if (tid < 64) {
    #pragma unroll
    for (int j = 0; j < 5; ++j)
      rn1v[j] = rn1[((size_t)b * P_DIM + pgi * 5 + j) * L_DIM + l0 + tid];
  }

  // X1 build: bf16( s1 * k^2 ), swizzled 8B stores (rn1 applied at output)
  auto build = [&](unsigned short* dst, int j) {
    const float4 kv = kv2[j];
    #pragma unroll
    for (int i = 0; i < 8; ++i) {
      const int row = i * 8 + wave;
      float x0 = __uint_as_float(s1r[i].x << 16)         * kv.x;
      float x1 = __uint_as_float(s1r[i].x & 0xffff0000u) * kv.y;
      float x2 = __uint_as_float(s1r[i].y << 16)         * kv.z;
      float x3 = __uint_as_float(s1r[i].y & 0xffff0000u) * kv.w;
      unsigned int c0 = ((unsigned int)f2bf(x1) << 16) | f2bf(x0);
      unsigned int c1 = ((unsigned int)f2bf(x3) << 16) | f2bf(x2);
      *(uint2*)&dst[row * 256 + (((lane >> 1) ^ (row & 31)) << 3) + ((lane & 1) << 2)] =
          make_uint2(c0, c1);
    }
  };

  build(X1[0], 0);       // prologue: p0 into buffer 0
  __syncthreads();

  int par = 0;
  #pragma unroll 1
  for (int pp = 0; pp < 5; ++pp) {
    const int p = pgi * 5 + pp;

    // issue rn2 loads early — consumed after the K-loop (~2500cy of cover)
    const float* rn2b = rn2 + ((size_t)b * P_DIM + p) * L_DIM + wave * 32;
    float4 r20 = *(const float4*)(rn2b + q * 4);
    float4 r21 = *(const float4*)(rn2b + 16 + q * 4);

    // build next p's X1 into the other buffer; overlaps this p's K-loop
    if (pp < 4) build(X1[par ^ 1], pp + 1);

    // K-loop: wave computes C[32m x 64l], A from registers, B from LDS
    f32x4 acc[2][4];
    #pragma unroll
    for (int mi = 0; mi < 2; ++mi)
      #pragma unroll
      for (int li = 0; li < 4; ++li) acc[mi][li] = (f32x4){0.f, 0.f, 0.f, 0.f};

    const unsigned short* Xc = X1[par];
    #pragma unroll
    for (int ks = 0; ks < 8; ++ks) {
      const int cc = ks * 4 + q;
      bf16x8 bb[4];
      #pragma unroll
      for (int li = 0; li < 4; ++li) {
        const int l = li * 16 + lr;
        bb[li] = *(const bf16x8*)&Xc[l * 256 + ((cc ^ (l & 31)) << 3)];
      }
      #pragma unroll
      for (int li = 0; li < 4; ++li) {
        acc[0][li] = __builtin_amdgcn_mfma_f32_16x16x32_bf16(af[0][ks], bb[li], acc[0][li], 0, 0, 0);
        acc[1][li] = __builtin_amdgcn_mfma_f32_16x16x32_bf16(af[1][ks], bb[li], acc[1][li], 0, 0, 0);
      }
    }

    // epilogue: C row(reg) = m = wave*32 + mi*16 + q*4 + r ; col(lane) = l = li*16+lr
    float v[4];
    #pragma unroll
    for (int li = 0; li < 4; ++li) {
      float t = -3.4e38f;
      t = fmaxf(t, fmaxf(acc[0][li][0] * r20.x, acc[1][li][0] * r21.x));
      t = fmaxf(t, fmaxf(acc[0][li][1] * r20.y, acc[1][li][1] * r21.y));
      t = fmaxf(t, fmaxf(acc[0][li][2] * r20.z, acc[1][li][2] * r21.z));
      t = fmaxf(t, fmaxf(acc[0][li][3] * r20.w, acc[1][li][3] * r21.w));
      t = fmaxf(t, __shfl_xor(t, 16));
      t = fmaxf(t, __shfl_xor(t, 32));
      v[li] = t;
    }
    if (q == 0) {
      #pragma unroll
      for (int li = 0; li < 4; ++li) Wout[par][wave * 64 + li * 16 + lr] = v[li];
    }
    __syncthreads();   // the ONE barrier: X1[par] reads done, X1[par^1] built, Wout[par] visible
    if (tid < 64) {
      float o = Wout[par][tid];
      #pragma unroll
      for (int w = 1; w < 8; ++w) o = fmaxf(o, Wout[par][w * 64 + tid]);
      outg[((size_t)b * L_DIM + (l0 + tid)) * P_DIM + p] = o * rn1v[pp];
    }
    par ^= 1;
  }
}

extern "C" void kernel_launch(void* const* d_in, const int* in_sizes, int n_in,
                              void* d_out, int out_size, void* d_ws, size_t ws_size,
                              hipStream_t stream) {
  (void)in_sizes; (void)n_in; (void)out_size; (void)ws_size;
  const float* s1 = (const float*)d_in[0];
  const float* s2 = (const float*)d_in[1];
  const float* kg = (const float*)d_in[2];
  float* out = (float*)d_out;

  // ws: rn1 | rn2 (B*P*L f32 each) | s2bf | s1bf (B*L*D bf16 each)  ≈ 4.9 MB
  float* rn1 = (float*)d_ws;
  float* rn2 = rn1 + (size_t)B_DIM * P_DIM * L_DIM;
  unsigned short* s2bf = (unsigned short*)(rn2 + (size_t)B_DIM * P_DIM * L_DIM);
  unsigned short* s1bf = s2bf + (size_t)B_DIM * L_DIM * D_DIM;

  prep2<<<dim3(256), dim3(256), 0, stream>>>(s1, s2, kg, rn1, rn2, s1bf, s2bf);
  mpm_main<<<dim3(256), dim3(512), 0, stream>>>(s1bf, s2bf, kg, rn1, rn2, out);
}